// Round 4
// baseline (14137.383 us; speedup 1.0000x reference)
//
#include <hip/hip_runtime.h>
#include <math.h>

#define N_PTS 16384
#define KNN_K 32
#define KEEP 48          // fp32 candidate list; re-scored np-style, top-32 kept
#define HDIM 128

// ---------------------------------------------------------------------------
// numpy-pairwise fp32 sum of squares per row: replicates np.sum(x*x, axis=1)
// (8 accumulators over the contiguous axis, tree-combined), with rounding
// locked via __fmul_rn/__fadd_rn so -ffp-contract can't fuse.
template<int C>
__global__ void sqnorm_np_kernel(const float* __restrict__ feat, float* __restrict__ sq) {
  int r = blockIdx.x * 256 + threadIdx.x;
  if (r >= N_PTS) return;
  const float* xr = feat + (size_t)r * C;
  float acc[8];
  #pragma unroll
  for (int j = 0; j < 8; j++) acc[j] = __fmul_rn(xr[j], xr[j]);
  for (int i = 8; i < C; i += 8) {
    #pragma unroll
    for (int j = 0; j < 8; j++)
      acc[j] = __fadd_rn(acc[j], __fmul_rn(xr[i + j], xr[i + j]));
  }
  float s01 = __fadd_rn(acc[0], acc[1]);
  float s23 = __fadd_rn(acc[2], acc[3]);
  float s45 = __fadd_rn(acc[4], acc[5]);
  float s67 = __fadd_rn(acc[6], acc[7]);
  sq[r] = __fadd_rn(__fadd_rn(s01, s23), __fadd_rn(s45, s67));
}

// ---------------------------------------------------------------------------
// KNN pass 1 (fp32 candidates): 64 queries/block vs candidates in chunks of 64.
// Register-tiled 64x64 distance GEMM (4x4/thread); 64 selection threads keep
// the KEEP smallest in registers. Only SET membership in the top-KEEP matters;
// gap(rank32 -> rank48) >> all fp32 noise, so the np-fp32 top-32 is inside.
template<int C>
__launch_bounds__(256)
__global__ void knn_kernel(const float* __restrict__ feat, const float* __restrict__ sq,
                           int* __restrict__ cand_out) {
  constexpr int QI = 64, NJ = 64;
  constexpr int KCH = (C == 64) ? 64 : 32;
  constexpr int SPA = C + 4;
  constexpr int SPB = KCH + 4;
  __shared__ float Aq[QI * SPA];
  __shared__ float Bt[NJ * SPB];
  __shared__ float Dist[QI * 65];
  __shared__ float sqq[QI];

  const int t = threadIdx.x;
  const int qbase = blockIdx.x * QI;
  const int tx = t & 15, ty = t >> 4;

  for (int v = t; v < QI * C / 4; v += 256) {
    int r = v / (C / 4), c4 = v % (C / 4);
    float4 f = *(const float4*)(feat + (size_t)(qbase + r) * C + c4 * 4);
    *(float4*)(&Aq[r * SPA + c4 * 4]) = f;
  }
  if (t < QI) sqq[t] = sq[qbase + t];

  float ld[KEEP]; int li[KEEP];
  #pragma unroll
  for (int s = 0; s < KEEP; s++) { ld[s] = INFINITY; li[s] = 0; }
  float maxv = INFINITY; int maxp = 0;

  for (int j0 = 0; j0 < N_PTS; j0 += NJ) {
    float acc[4][4] = {};
    for (int kc = 0; kc < C; kc += KCH) {
      __syncthreads();
      for (int v = t; v < NJ * KCH / 4; v += 256) {
        int r = v / (KCH / 4), c4 = v % (KCH / 4);
        float4 f = *(const float4*)(feat + (size_t)(j0 + r) * C + kc + c4 * 4);
        *(float4*)(&Bt[r * SPB + c4 * 4]) = f;
      }
      __syncthreads();
      #pragma unroll
      for (int kk = 0; kk < KCH; kk += 4) {
        float4 a[4], b[4];
        #pragma unroll
        for (int i = 0; i < 4; i++) a[i] = *(const float4*)(&Aq[(ty + 16*i)*SPA + kc + kk]);
        #pragma unroll
        for (int i = 0; i < 4; i++) b[i] = *(const float4*)(&Bt[(tx + 16*i)*SPB + kk]);
        #pragma unroll
        for (int i = 0; i < 4; i++)
          #pragma unroll
          for (int j = 0; j < 4; j++)
            acc[i][j] += a[i].x*b[j].x + a[i].y*b[j].y + a[i].z*b[j].z + a[i].w*b[j].w;
      }
    }
    #pragma unroll
    for (int i = 0; i < 4; i++) {
      float si = sqq[ty + 16*i];
      #pragma unroll
      for (int j = 0; j < 4; j++) {
        int c = tx + 16*j;
        Dist[(ty + 16*i)*65 + c] = si + sq[j0 + c] - 2.f*acc[i][j];
      }
    }
    __syncthreads();
    if (t < QI) {
      const int gi = qbase + t;
      for (int c = 0; c < NJ; c++) {
        float d = Dist[t*65 + c];
        int j = j0 + c;
        if (d < maxv && j != gi) {
          #pragma unroll
          for (int s = 0; s < KEEP; s++) if (s == maxp) { ld[s] = d; li[s] = j; }
          float m = -INFINITY; int mp = 0;
          #pragma unroll
          for (int s = 0; s < KEEP; s++) if (ld[s] > m) { m = ld[s]; mp = s; }
          maxv = m; maxp = mp;
        }
      }
    }
  }
  if (t < QI) {
    const int gi = qbase + t;
    #pragma unroll
    for (int s = 0; s < KEEP; s++) cand_out[(size_t)gi * KEEP + s] = li[s];
  }
}

// ---------------------------------------------------------------------------
// KNN pass 2 (np-fp32 refine): re-score each candidate EXACTLY as numpy does:
// G = sequential fp32 fma chain over c (BLAS microkernel order);
// d = fl32(fl32(sq_q + sq_j) - fl32(2*G)); rank by (d, index) — reproducing
// top_k's lower-index-first tie-break on exact fp32 ties.
template<int C>
__global__ void knn_refine_np(const float* __restrict__ feat, const float* __restrict__ sq,
                              const int* __restrict__ cand, int* __restrict__ idx_out) {
  __shared__ float ds[4][KEEP];
  __shared__ int   js[4][KEEP];
  const int w = threadIdx.x >> 6;
  const int lane = threadIdx.x & 63;
  const int q = blockIdx.x * 4 + w;
  float d = 0.f; int j = 0x7fffffff;
  if (lane < KEEP) {
    j = cand[(size_t)q * KEEP + lane];
    const float* xq = feat + (size_t)q * C;
    const float* xj = feat + (size_t)j * C;
    float g = 0.f;
    for (int c = 0; c < C; c++) g = fmaf(xq[c], xj[c], g);
    d = __fsub_rn(__fadd_rn(sq[q], sq[j]), __fmul_rn(2.f, g));
    ds[w][lane] = d; js[w][lane] = j;
  }
  __syncthreads();
  if (lane < KEEP) {
    int rank = 0;
    #pragma unroll
    for (int m = 0; m < KEEP; m++) {
      float dm = ds[w][m]; int jm = js[w][m];
      if (dm < d || (dm == d && jm < j)) rank++;
    }
    if (rank < KNN_K) idx_out[(size_t)q * KNN_K + rank] = j;
  }
}

// ---------------------------------------------------------------------------
// P[n][ch] = b[ch] + x[n]@(Wtop - Wbot)[:,ch];  Q[n][ch] = x[n]@Wbot[:,ch].
// One thread per (n,ch), fp64 accumulation. W is (2C x 128) row-major.
template<int C>
__global__ void pq_kernel(const float* __restrict__ feat, const float* __restrict__ W,
                          const float* __restrict__ b, float* __restrict__ P,
                          float* __restrict__ Q) {
  int gid = blockIdx.x * 256 + threadIdx.x;   // N*128 threads
  int n = gid >> 7, ch = gid & 127;
  const float* xr = feat + (size_t)n * C;
  double p = (double)b[ch], q = 0.0;
  for (int d = 0; d < C; d++) {
    double xv = (double)xr[d];
    p += xv * (double)W[(size_t)d * HDIM + ch];            // Wtop
    q += xv * (double)W[(size_t)(C + d) * HDIM + ch];      // Wbot
  }
  P[gid] = (float)(p - q);
  Q[gid] = (float)q;
}

// ---------------------------------------------------------------------------
// h[n,k,ch] = relu(P[n,ch] + Q[idx[n,k],ch]); per-(n,ch) max/min over k;
// per-channel fp64 sum/sumsq via block reduction + one double atomic per ch.
__global__ void edge_gather2(const float* __restrict__ P, const float* __restrict__ Q,
                             const int* __restrict__ idx, float* __restrict__ hmax,
                             float* __restrict__ hmin, double* __restrict__ stats) {
  __shared__ double red0[256];
  __shared__ double red1[256];
  const int t = threadIdx.x;           // 256 = 2 half-threads x 128 ch
  const int ch = t & 127, half = t >> 7;
  const size_t nb = (size_t)blockIdx.x * 16 + (size_t)half * 8;
  double s = 0.0, s2 = 0.0;
  for (int u = 0; u < 8; u++) {
    const size_t n = nb + u;
    double p = (double)P[n * 128 + ch];
    double mx = -1.0e300, mn = 1.0e300;
    for (int k = 0; k < KNN_K; k++) {
      int j = idx[n * KNN_K + k];
      double h = p + (double)Q[(size_t)j * 128 + ch];
      h = h > 0.0 ? h : 0.0;
      mx = h > mx ? h : mx;
      mn = h < mn ? h : mn;
      s += h; s2 += h * h;
    }
    hmax[n * 128 + ch] = (float)mx;
    hmin[n * 128 + ch] = (float)mn;
  }
  red0[t] = s; red1[t] = s2;
  __syncthreads();
  if (t < 128) {
    atomicAdd(&stats[ch],       red0[t] + red0[t + 128]);
    atomicAdd(&stats[128 + ch], red1[t] + red1[t + 128]);
  }
}

__global__ void zero_stats_d(double* __restrict__ stats) {
  stats[threadIdx.x] = 0.0;   // 256 doubles
}

__global__ void bn_finalize_d(const double* __restrict__ stats, const float* __restrict__ g,
                              const float* __restrict__ beta, double* __restrict__ ss) {
  int ch = threadIdx.x;  // 128
  const double inv = 1.0 / ((double)N_PTS * (double)KNN_K);
  double mu = stats[ch] * inv;
  double var = stats[128 + ch] * inv - mu * mu;
  double sc = (double)g[ch] / sqrt(var + 1e-5);
  ss[ch] = sc;
  ss[128 + ch] = (double)beta[ch] - mu * sc;
}

// out = (sc>=0 ? hmax : hmin)*sc + shift  == max_k of the normalized h.
__global__ void ec_out_d(const float* __restrict__ hmax, const float* __restrict__ hmin,
                         const double* __restrict__ ss, float* __restrict__ h_f) {
  size_t i = (size_t)blockIdx.x * 256 + threadIdx.x;
  int ch = (int)(i & 127);
  double sc = ss[ch];
  double v = sc >= 0.0 ? (double)hmax[i] : (double)hmin[i];
  h_f[i] = (float)(v * sc + ss[128 + ch]);
}

// ---------------------------------------------------------------------------
// Head, naive fp64: T = relu(relu(h2) @ lw1 + lb1); out = T @ lw2 + lb2.
__global__ void head1_kernel(const float* __restrict__ h2, const float* __restrict__ lw1,
                             const float* __restrict__ lb1, float* __restrict__ T) {
  int gid = blockIdx.x * 256 + threadIdx.x;  // N*64
  int n = gid >> 6, hc = gid & 63;
  const float* hr = h2 + (size_t)n * 128;
  double a = (double)lb1[hc];
  for (int d = 0; d < 128; d++) {
    double v = (double)hr[d];
    v = v > 0.0 ? v : 0.0;
    a += v * (double)lw1[(size_t)d * 64 + hc];
  }
  T[gid] = (float)(a > 0.0 ? a : 0.0);
}

__global__ void head2_kernel(const float* __restrict__ T, const float* __restrict__ lw2,
                             const float* __restrict__ lb2, float* __restrict__ out) {
  int gid = blockIdx.x * 256 + threadIdx.x;  // N*64
  int n = gid >> 6, oc = gid & 63;
  const float* tr = T + (size_t)n * 64;
  double a = (double)lb2[oc];
  for (int d = 0; d < 64; d++) a += (double)tr[d] * (double)lw2[(size_t)d * 64 + oc];
  out[gid] = (float)a;
}

// ---------------------------------------------------------------------------
extern "C" void kernel_launch(void* const* d_in, const int* in_sizes, int n_in,
                              void* d_out, int out_size, void* d_ws, size_t ws_size,
                              hipStream_t stream) {
  (void)in_sizes; (void)n_in; (void)out_size; (void)ws_size;
  const float* x     = (const float*)d_in[0];
  const float* W1    = (const float*)d_in[1];
  const float* b1    = (const float*)d_in[2];
  const float* g1    = (const float*)d_in[3];
  const float* beta1 = (const float*)d_in[4];
  const float* W2    = (const float*)d_in[5];
  const float* b2    = (const float*)d_in[6];
  const float* g2    = (const float*)d_in[7];
  const float* beta2 = (const float*)d_in[8];
  const float* lw1   = (const float*)d_in[9];
  const float* lb1   = (const float*)d_in[10];
  const float* lw2   = (const float*)d_in[11];
  const float* lb2   = (const float*)d_in[12];
  float* out = (float*)d_out;

  char* w = (char*)d_ws;
  size_t off = 0;
  auto alloc = [&](size_t bytes) { char* p = w + off; off += (bytes + 255) & ~(size_t)255; return p; };
  float*  sq    = (float*) alloc(N_PTS * 4);                    //  64 KB
  int*    cand  = (int*)   alloc((size_t)N_PTS * KEEP * 4);     //   3 MB
  int*    idx   = (int*)   alloc((size_t)N_PTS * KNN_K * 4);    //   2 MB
  float*  P     = (float*) alloc((size_t)N_PTS * HDIM * 4);     //   8 MB
  float*  Q     = (float*) alloc((size_t)N_PTS * HDIM * 4);     //   8 MB
  float*  hmax  = (float*) alloc((size_t)N_PTS * HDIM * 4);     //   8 MB
  float*  hmin  = (float*) alloc((size_t)N_PTS * HDIM * 4);     //   8 MB
  double* stats = (double*)alloc(2 * HDIM * 8);                 //   2 KB
  double* ss    = (double*)alloc(2 * HDIM * 8);                 //   2 KB
  float*  h1f   = (float*) alloc((size_t)N_PTS * HDIM * 4);     //   8 MB
  float*  h2f   = P;                                            // reuse (P dead after gather2)
  float*  T     = Q;                                            // reuse (Q dead after gather2)

  // ---- stage 1: knn on x (C=64), np-fp32-exact selection ----
  sqnorm_np_kernel<64><<<N_PTS / 256, 256, 0, stream>>>(x, sq);
  knn_kernel<64><<<N_PTS / 64, 256, 0, stream>>>(x, sq, cand);
  knn_refine_np<64><<<N_PTS / 4, 256, 0, stream>>>(x, sq, cand, idx);

  // ---- edge conv 1 (fp64) ----
  pq_kernel<64><<<N_PTS * 128 / 256, 256, 0, stream>>>(x, W1, b1, P, Q);
  zero_stats_d<<<1, 256, 0, stream>>>(stats);
  edge_gather2<<<N_PTS / 16, 256, 0, stream>>>(P, Q, idx, hmax, hmin, stats);
  bn_finalize_d<<<1, 128, 0, stream>>>(stats, g1, beta1, ss);
  ec_out_d<<<N_PTS * HDIM / 256, 256, 0, stream>>>(hmax, hmin, ss, h1f);

  // ---- stage 2: knn on h1 (C=128), np-fp32-exact selection ----
  sqnorm_np_kernel<128><<<N_PTS / 256, 256, 0, stream>>>(h1f, sq);
  knn_kernel<128><<<N_PTS / 64, 256, 0, stream>>>(h1f, sq, cand);
  knn_refine_np<128><<<N_PTS / 4, 256, 0, stream>>>(h1f, sq, cand, idx);

  // ---- edge conv 2 (fp64) ----
  pq_kernel<128><<<N_PTS * 128 / 256, 256, 0, stream>>>(h1f, W2, b2, P, Q);
  zero_stats_d<<<1, 256, 0, stream>>>(stats);
  edge_gather2<<<N_PTS / 16, 256, 0, stream>>>(P, Q, idx, hmax, hmin, stats);
  bn_finalize_d<<<1, 128, 0, stream>>>(stats, g2, beta2, ss);
  ec_out_d<<<N_PTS * HDIM / 256, 256, 0, stream>>>(hmax, hmin, ss, h2f);

  // ---- head (fp64) ----
  head1_kernel<<<N_PTS * 64 / 256, 256, 0, stream>>>(h2f, lw1, lb1, T);
  head2_kernel<<<N_PTS * 64 / 256, 256, 0, stream>>>(T, lw2, lb2, out);
}